// Round 3
// baseline (7201.320 us; speedup 1.0000x reference)
//
#include <hip/hip_runtime.h>
#include <stdint.h>

typedef __attribute__((ext_vector_type(8))) short bf16x8;
typedef __attribute__((ext_vector_type(4))) float f32x4;

static __device__ __forceinline__ float b2f_lo(uint32_t w) {
  union { uint32_t u; float f; } c; c.u = w << 16; return c.f;
}
static __device__ __forceinline__ float b2f_hi(uint32_t w) {
  union { uint32_t u; float f; } c; c.u = w & 0xffff0000u; return c.f;
}
static __device__ __forceinline__ uint16_t f2b(float f) {
  union { float f; uint32_t u; } c; c.f = f;
  return (uint16_t)((c.u + 0x7fffu + ((c.u >> 16) & 1u)) >> 16);
}

// load 4 consecutive dims as fp32, from either fp32 or bf16 storage
static __device__ __forceinline__ f32x4 load4f(const float* p) {
  return *(const f32x4*)p;
}
static __device__ __forceinline__ f32x4 load4f(const uint16_t* p) {
  uint2 t = *(const uint2*)p;
  f32x4 r;
  r.x = b2f_lo(t.x); r.y = b2f_hi(t.x);
  r.z = b2f_lo(t.y); r.w = b2f_hi(t.y);
  return r;
}

// load 8 consecutive dims as bf16 fragment, from either fp32 or bf16 storage
static __device__ __forceinline__ bf16x8 load8b(const float* p) {
  f32x4 a = *(const f32x4*)p;
  f32x4 b = *(const f32x4*)(p + 4);
  bf16x8 r;
  r[0] = (short)f2b(a.x); r[1] = (short)f2b(a.y);
  r[2] = (short)f2b(a.z); r[3] = (short)f2b(a.w);
  r[4] = (short)f2b(b.x); r[5] = (short)f2b(b.y);
  r[6] = (short)f2b(b.z); r[7] = (short)f2b(b.w);
  return r;
}
static __device__ __forceinline__ bf16x8 load8b(const uint16_t* p) {
  return *(const bf16x8*)p;
}

// ---------------- in-degree counts (both relations, disjoint dst regions) ---
__global__ void count_kernel(const int* __restrict__ pt_dst,
                             const int* __restrict__ tp_dst,
                             int* __restrict__ cnt, int E, int NP) {
  int i = blockIdx.x * blockDim.x + threadIdx.x;
  if (i >= 2 * E) return;
  int d = (i < E) ? (NP + pt_dst[i]) : tp_dst[i - E];
  atomicAdd(&cnt[d], 1);
}

// ---------------- push-scatter: agg[dst] += x[src] (fp32 atomics) -----------
// 16 threads per edge, 4 dims per thread.
template <typename T>
__global__ void scatter_kernel(const int* __restrict__ pt_src,
                               const int* __restrict__ pt_dst,
                               const int* __restrict__ tp_src,
                               const int* __restrict__ tp_dst,
                               const T* __restrict__ pl_base,
                               const T* __restrict__ tr_base,
                               float* __restrict__ agg, int E, int NP) {
  long g = (long)blockIdx.x * blockDim.x + threadIdx.x;
  long edge = g >> 4;
  int sub = (int)(g & 15);
  if (edge >= 2L * E) return;
  const T* srow;
  int dstn;
  if (edge < E) {
    srow = pl_base + (size_t)pt_src[edge] * 64;
    dstn = NP + pt_dst[edge];
  } else {
    long e2 = edge - E;
    srow = tr_base + (size_t)tp_src[e2] * 64;
    dstn = tp_dst[e2];
  }
  f32x4 v = load4f(srow + sub * 4);
  float* arow = agg + (size_t)dstn * 64 + sub * 4;
  atomicAdd(arow + 0, v.x);
  atomicAdd(arow + 1, v.y);
  atomicAdd(arow + 2, v.z);
  atomicAdd(arow + 3, v.w);
}

// ---------------- fused transform: xout = relu(x@Wroot + (agg/cnt)@Wrel + b)
// MFMA 16x16x32 bf16, fp32 accumulate. Blocks [0,BP) playlist tiles, rest track.
template <typename XT>
__global__ __launch_bounds__(256) void transform_kernel(
    const XT* __restrict__ xpl, const XT* __restrict__ xtr,
    const float* __restrict__ agg, const int* __restrict__ cnt,
    const float* __restrict__ Wroot,
    const float* __restrict__ WrelP, const float* __restrict__ WrelT,
    const float* __restrict__ biasrow,
    uint16_t* __restrict__ xout, int NP, int NT, int BP) {
  int wave = threadIdx.x >> 6;
  int lane = threadIdx.x & 63;
  int m = lane & 15, q = lane >> 4;

  int wl, nw, ntiles, nodeBase;
  const XT* xbase;
  const float* Wrel;
  if ((int)blockIdx.x < BP) {
    wl = blockIdx.x * 4 + wave; nw = BP * 4; ntiles = NP / 16;
    xbase = xpl; Wrel = WrelP; nodeBase = 0;
  } else {
    wl = (blockIdx.x - BP) * 4 + wave; nw = (gridDim.x - BP) * 4; ntiles = NT / 16;
    xbase = xtr; Wrel = WrelT; nodeBase = NP;
  }

  // B fragments: B[k][n], lane n=16*ct+m, elems k=32*kc+8*q+i
  bf16x8 br[2][4], bl[2][4];
  for (int kc = 0; kc < 2; ++kc)
    for (int ct = 0; ct < 4; ++ct) {
      int n = 16 * ct + m;
      int k0 = 32 * kc + 8 * q;
      bf16x8 t0, t1;
      for (int i = 0; i < 8; ++i) {
        t0[i] = (short)f2b(Wroot[(size_t)(k0 + i) * 64 + n]);
        t1[i] = (short)f2b(Wrel[(size_t)(k0 + i) * 64 + n]);
      }
      br[kc][ct] = t0;
      bl[kc][ct] = t1;
    }
  float bv[4];
  for (int ct = 0; ct < 4; ++ct) bv[ct] = biasrow[16 * ct + m];

  for (int t = wl; t < ntiles; t += nw) {
    int rowLocal = t * 16 + m;  // A row: m = lane&15
    int nodeG = nodeBase + rowLocal;
    const XT* xrow = xbase + (size_t)rowLocal * 64;
    bf16x8 ax0 = load8b(xrow + 8 * q);
    bf16x8 ax1 = load8b(xrow + 32 + 8 * q);

    int c = cnt[nodeG];
    float inv = 1.0f / (float)(c > 1 ? c : 1);
    const float* arow = agg + (size_t)nodeG * 64;
    bf16x8 aa0, aa1;
#pragma unroll
    for (int i = 0; i < 8; ++i) aa0[i] = (short)f2b(arow[8 * q + i] * inv);
#pragma unroll
    for (int i = 0; i < 8; ++i) aa1[i] = (short)f2b(arow[32 + 8 * q + i] * inv);

    f32x4 acc[4];
#pragma unroll
    for (int ct = 0; ct < 4; ++ct) acc[ct] = (f32x4){bv[ct], bv[ct], bv[ct], bv[ct]};
#pragma unroll
    for (int ct = 0; ct < 4; ++ct) {
      acc[ct] = __builtin_amdgcn_mfma_f32_16x16x32_bf16(ax0, br[0][ct], acc[ct], 0, 0, 0);
      acc[ct] = __builtin_amdgcn_mfma_f32_16x16x32_bf16(ax1, br[1][ct], acc[ct], 0, 0, 0);
      acc[ct] = __builtin_amdgcn_mfma_f32_16x16x32_bf16(aa0, bl[0][ct], acc[ct], 0, 0, 0);
      acc[ct] = __builtin_amdgcn_mfma_f32_16x16x32_bf16(aa1, bl[1][ct], acc[ct], 0, 0, 0);
    }
    // D: row = 4*q + r, col = 16*ct + m
    int nodeRow0 = nodeBase + t * 16;
#pragma unroll
    for (int ct = 0; ct < 4; ++ct)
#pragma unroll
      for (int r = 0; r < 4; ++r) {
        float v = acc[ct][r];
        v = v > 0.0f ? v : 0.0f;
        xout[(size_t)(nodeRow0 + 4 * q + r) * 64 + 16 * ct + m] = f2b(v);
      }
  }
}

// ---------------- link scores: (1/9) * dot(sum_p, sum_t) --------------------
// 16 threads per pair, 4 dims each. fp32 output.
__global__ void score_kernel(const int* __restrict__ ell_pl,
                             const int* __restrict__ ell_tr,
                             const float* __restrict__ emb_pl,
                             const float* __restrict__ emb_tr,
                             const uint16_t* __restrict__ x1,
                             const uint16_t* __restrict__ x2,
                             float* __restrict__ out, int EP, int NP) {
  long g = (long)blockIdx.x * blockDim.x + threadIdx.x;
  long pair = g >> 4;
  int c = (int)(g & 15);
  if (pair >= EP) return;
  int p = ell_pl[pair];
  int t = ell_tr[pair];
  int d0 = c * 4;

  size_t pg = (size_t)p * 64 + d0;
  f32x4 sp = load4f(emb_pl + pg);
  f32x4 a = load4f(x1 + pg);
  f32x4 b = load4f(x2 + pg);
  sp.x += a.x + b.x; sp.y += a.y + b.y; sp.z += a.z + b.z; sp.w += a.w + b.w;

  size_t tl = (size_t)t * 64 + d0;
  size_t tg = (size_t)(NP + t) * 64 + d0;
  f32x4 st = load4f(emb_tr + tl);
  a = load4f(x1 + tg);
  b = load4f(x2 + tg);
  st.x += a.x + b.x; st.y += a.y + b.y; st.z += a.z + b.z; st.w += a.w + b.w;

  float partial = sp.x * st.x + sp.y * st.y + sp.z * st.z + sp.w * st.w;
  partial += __shfl_xor(partial, 1);
  partial += __shfl_xor(partial, 2);
  partial += __shfl_xor(partial, 4);
  partial += __shfl_xor(partial, 8);
  if (c == 0) out[pair] = partial * (1.0f / 9.0f);
}

extern "C" void kernel_launch(void* const* d_in, const int* in_sizes, int n_in,
                              void* d_out, int out_size, void* d_ws, size_t ws_size,
                              hipStream_t stream) {
  const float* emb_pl = (const float*)d_in[0];
  const float* emb_tr = (const float*)d_in[1];
  const float* W_rel = (const float*)d_in[2];   // [L,2,64,64] f32
  const float* W_root = (const float*)d_in[3];  // [L,64,64] f32
  const float* bias = (const float*)d_in[4];    // [L,64] f32
  const int* pt_src = (const int*)d_in[7];
  const int* pt_dst = (const int*)d_in[8];
  const int* tp_src = (const int*)d_in[9];
  const int* tp_dst = (const int*)d_in[10];
  const int* ell_pl = (const int*)d_in[11];
  const int* ell_tr = (const int*)d_in[12];
  float* out = (float*)d_out;

  const int NP = in_sizes[5];
  const int NT = in_sizes[6];
  const int E = in_sizes[7];
  const int EP = in_sizes[11];
  const int N = NP + NT;

  char* ws = (char*)d_ws;
  float* agg = (float*)ws;                       // [N,64] f32
  size_t off = (size_t)N * 64 * sizeof(float);
  uint16_t* x1 = (uint16_t*)(ws + off);          // [N,64] bf16
  off += (size_t)N * 64 * 2;
  uint16_t* x2 = (uint16_t*)(ws + off);          // [N,64] bf16
  off += (size_t)N * 64 * 2;
  int* cnt = (int*)(ws + off);                   // [N] i32

  const int TB = 256;
  int cntBlocks = (2 * E + TB - 1) / TB;
  long scatterThreads = 2L * E * 16;
  int scatterBlocks = (int)((scatterThreads + TB - 1) / TB);
  int scoreBlocks = (int)(((long)EP * 16 + TB - 1) / TB);
  const int BP = 256, GT = 1024;  // transform grid split playlist/track

  hipMemsetAsync(cnt, 0, (size_t)N * 4, stream);
  count_kernel<<<cntBlocks, TB, 0, stream>>>(pt_dst, tp_dst, cnt, E, NP);

  // ---- layer 0 (x = fp32 embeddings) ----
  hipMemsetAsync(agg, 0, (size_t)N * 64 * 4, stream);
  scatter_kernel<float><<<scatterBlocks, TB, 0, stream>>>(
      pt_src, pt_dst, tp_src, tp_dst, emb_pl, emb_tr, agg, E, NP);
  // playlist region receives relation tp (r=1); track region relation pt (r=0)
  transform_kernel<float><<<GT, TB, 0, stream>>>(
      emb_pl, emb_tr, agg, cnt, W_root + 0 * 4096, W_rel + 1 * 4096,
      W_rel + 0 * 4096, bias + 0, x1, NP, NT, BP);

  // ---- layer 1 (x = x1, bf16 internal) ----
  hipMemsetAsync(agg, 0, (size_t)N * 64 * 4, stream);
  scatter_kernel<uint16_t><<<scatterBlocks, TB, 0, stream>>>(
      pt_src, pt_dst, tp_src, tp_dst, x1, x1 + (size_t)NP * 64, agg, E, NP);
  transform_kernel<uint16_t><<<GT, TB, 0, stream>>>(
      x1, x1 + (size_t)NP * 64, agg, cnt, W_root + 1 * 4096, W_rel + 3 * 4096,
      W_rel + 2 * 4096, bias + 64, x2, NP, NT, BP);

  // ---- link scores ----
  score_kernel<<<scoreBlocks, TB, 0, stream>>>(ell_pl, ell_tr, emb_pl, emb_tr,
                                               x1, x2, out, EP, NP);
}

// Round 4
// 1066.883 us; speedup vs baseline: 6.7499x; 6.7499x over previous
//
#include <hip/hip_runtime.h>
#include <stdint.h>

typedef __attribute__((ext_vector_type(8))) short bf16x8;
typedef __attribute__((ext_vector_type(4))) float f32x4;

static __device__ __forceinline__ float b2f_lo(uint32_t w) {
  union { uint32_t u; float f; } c; c.u = w << 16; return c.f;
}
static __device__ __forceinline__ float b2f_hi(uint32_t w) {
  union { uint32_t u; float f; } c; c.u = w & 0xffff0000u; return c.f;
}
static __device__ __forceinline__ uint16_t f2b(float f) {
  union { float f; uint32_t u; } c; c.f = f;
  return (uint16_t)((c.u + 0x7fffu + ((c.u >> 16) & 1u)) >> 16);
}

static __device__ __forceinline__ f32x4 load4f(const float* p) {
  return *(const f32x4*)p;
}
static __device__ __forceinline__ f32x4 load4f(const uint16_t* p) {
  uint2 t = *(const uint2*)p;
  f32x4 r;
  r.x = b2f_lo(t.x); r.y = b2f_hi(t.x);
  r.z = b2f_lo(t.y); r.w = b2f_hi(t.y);
  return r;
}

static __device__ __forceinline__ float loadElem(const float* p) { return *p; }
static __device__ __forceinline__ float loadElem(const uint16_t* p) {
  union { uint32_t u; float f; } c; c.u = ((uint32_t)(*p)) << 16; return c.f;
}

static __device__ __forceinline__ bf16x8 load8b(const float* p) {
  f32x4 a = *(const f32x4*)p;
  f32x4 b = *(const f32x4*)(p + 4);
  bf16x8 r;
  r[0] = (short)f2b(a.x); r[1] = (short)f2b(a.y);
  r[2] = (short)f2b(a.z); r[3] = (short)f2b(a.w);
  r[4] = (short)f2b(b.x); r[5] = (short)f2b(b.y);
  r[6] = (short)f2b(b.z); r[7] = (short)f2b(b.w);
  return r;
}
static __device__ __forceinline__ bf16x8 load8b(const uint16_t* p) {
  return *(const bf16x8*)p;
}

// ---------------- degree counts (both relations, disjoint dst regions) ------
__global__ void count_kernel(const int* __restrict__ pt_dst,
                             const int* __restrict__ tp_dst,
                             int* __restrict__ cnt, int E, int NP) {
  int i = blockIdx.x * blockDim.x + threadIdx.x;
  if (i >= 2 * E) return;
  int d = (i < E) ? (NP + pt_dst[i]) : tp_dst[i - E];
  atomicAdd(&cnt[d], 1);
}

// ---------------- prefix-scan (3 kernels, chunk=1024) -----------------------
__global__ __launch_bounds__(256) void partial_sum_kernel(
    const int* __restrict__ cnt, int* __restrict__ blockSums, int N) {
  __shared__ int sdata[256];
  int base = blockIdx.x * 1024;
  int s = 0;
  for (int i = threadIdx.x; i < 1024; i += 256) {
    int idx = base + i;
    s += (idx < N) ? cnt[idx] : 0;
  }
  sdata[threadIdx.x] = s;
  __syncthreads();
  for (int off = 128; off > 0; off >>= 1) {
    if (threadIdx.x < off) sdata[threadIdx.x] += sdata[threadIdx.x + off];
    __syncthreads();
  }
  if (threadIdx.x == 0) blockSums[blockIdx.x] = sdata[0];
}

__global__ __launch_bounds__(1024) void scan_sums_kernel(int* __restrict__ blockSums,
                                                         int nb) {
  __shared__ int s[1024];
  int t = threadIdx.x;
  int v = (t < nb) ? blockSums[t] : 0;
  int acc = v;
  s[t] = v;
  __syncthreads();
  for (int off = 1; off < 1024; off <<= 1) {
    int u = (t >= off) ? s[t - off] : 0;
    __syncthreads();
    acc += u;
    s[t] = acc;
    __syncthreads();
  }
  if (t < nb) blockSums[t] = acc - v;  // exclusive
}

__global__ __launch_bounds__(256) void scan_chunk_kernel(
    const int* __restrict__ cnt, const int* __restrict__ blockOffs,
    int* __restrict__ rowptr, int* __restrict__ wo, int N, int total) {
  __shared__ int ts[256];
  int base = blockIdx.x * 1024;
  int t = threadIdx.x;
  int v[4];
  int s = 0;
#pragma unroll
  for (int j = 0; j < 4; ++j) {
    int idx = base + t * 4 + j;
    v[j] = (idx < N) ? cnt[idx] : 0;
    s += v[j];
  }
  int acc = s;
  ts[t] = s;
  __syncthreads();
  for (int off = 1; off < 256; off <<= 1) {
    int u = (t >= off) ? ts[t - off] : 0;
    __syncthreads();
    acc += u;
    ts[t] = acc;
    __syncthreads();
  }
  int run = blockOffs[blockIdx.x] + (acc - s);
#pragma unroll
  for (int j = 0; j < 4; ++j) {
    int idx = base + t * 4 + j;
    if (idx < N) { rowptr[idx] = run; wo[idx] = run; }
    run += v[j];
  }
  if (blockIdx.x == 0 && t == 0) rowptr[N] = total;
}

// ---------------- CSR fill: col[pos] = global src ---------------------------
__global__ void fill_kernel(const int* __restrict__ pt_src,
                            const int* __restrict__ pt_dst,
                            const int* __restrict__ tp_src,
                            const int* __restrict__ tp_dst,
                            int* __restrict__ wo, int* __restrict__ col,
                            int E, int NP) {
  int e = blockIdx.x * blockDim.x + threadIdx.x;
  if (e >= 2 * E) return;
  int dst, src;
  if (e < E) { dst = NP + pt_dst[e]; src = pt_src[e]; }
  else       { dst = tp_dst[e - E];  src = NP + tp_src[e - E]; }
  int pos = atomicAdd(&wo[dst], 1);
  col[pos] = src;
}

// ---------------- pull aggregation: agg[n] = bf16(mean of src rows) ---------
// one wave per node, lane = dim. Source side is uniform per node (disjoint
// relations): node<NP pulls with basePl (pre-shifted), node>=NP with baseTr.
template <typename T>
__global__ __launch_bounds__(256) void pull_kernel(
    const int* __restrict__ rowptr, const int* __restrict__ col,
    const T* __restrict__ basePl, const T* __restrict__ baseTr,
    uint16_t* __restrict__ agg, int N, int NP) {
  int node = blockIdx.x * 4 + (threadIdx.x >> 6);
  int lane = threadIdx.x & 63;
  if (node >= N) return;
  int beg = rowptr[node], end = rowptr[node + 1];
  const T* base = (node < NP) ? basePl : baseTr;
  float s = 0.f;
  int i = beg;
  for (; i + 4 <= end; i += 4) {
    int c0 = col[i], c1 = col[i + 1], c2 = col[i + 2], c3 = col[i + 3];
    float v0 = loadElem(base + (size_t)c0 * 64 + lane);
    float v1 = loadElem(base + (size_t)c1 * 64 + lane);
    float v2 = loadElem(base + (size_t)c2 * 64 + lane);
    float v3 = loadElem(base + (size_t)c3 * 64 + lane);
    s += (v0 + v1) + (v2 + v3);
  }
  for (; i < end; ++i) s += loadElem(base + (size_t)col[i] * 64 + lane);
  int deg = end - beg;
  float inv = 1.0f / (float)(deg > 1 ? deg : 1);
  agg[(size_t)node * 64 + lane] = f2b(s * inv);
}

// ---------------- fused transform: xout = relu(x@Wroot + agg@Wrel + b) ------
// MFMA 16x16x32 bf16, fp32 accumulate. Blocks [0,BP) playlist tiles, rest track.
template <typename XT>
__global__ __launch_bounds__(256) void transform_kernel(
    const XT* __restrict__ xpl, const XT* __restrict__ xtr,
    const uint16_t* __restrict__ agg,
    const float* __restrict__ Wroot,
    const float* __restrict__ WrelP, const float* __restrict__ WrelT,
    const float* __restrict__ biasrow,
    uint16_t* __restrict__ xout, int NP, int NT, int BP) {
  int wave = threadIdx.x >> 6;
  int lane = threadIdx.x & 63;
  int m = lane & 15, q = lane >> 4;

  int wl, nw, ntiles, nodeBase;
  const XT* xbase;
  const float* Wrel;
  if ((int)blockIdx.x < BP) {
    wl = blockIdx.x * 4 + wave; nw = BP * 4; ntiles = NP / 16;
    xbase = xpl; Wrel = WrelP; nodeBase = 0;
  } else {
    wl = (blockIdx.x - BP) * 4 + wave; nw = (gridDim.x - BP) * 4; ntiles = NT / 16;
    xbase = xtr; Wrel = WrelT; nodeBase = NP;
  }

  // B fragments: B[k][n], lane n=16*ct+m, elems k=32*kc+8*q+i
  bf16x8 br[2][4], bl[2][4];
  for (int kc = 0; kc < 2; ++kc)
    for (int ct = 0; ct < 4; ++ct) {
      int n = 16 * ct + m;
      int k0 = 32 * kc + 8 * q;
      bf16x8 t0, t1;
      for (int i = 0; i < 8; ++i) {
        t0[i] = (short)f2b(Wroot[(size_t)(k0 + i) * 64 + n]);
        t1[i] = (short)f2b(Wrel[(size_t)(k0 + i) * 64 + n]);
      }
      br[kc][ct] = t0;
      bl[kc][ct] = t1;
    }
  float bv[4];
  for (int ct = 0; ct < 4; ++ct) bv[ct] = biasrow[16 * ct + m];

  for (int t = wl; t < ntiles; t += nw) {
    int rowLocal = t * 16 + m;  // A row: m = lane&15
    int nodeG = nodeBase + rowLocal;
    const XT* xrow = xbase + (size_t)rowLocal * 64;
    bf16x8 ax0 = load8b(xrow + 8 * q);
    bf16x8 ax1 = load8b(xrow + 32 + 8 * q);

    const uint16_t* arow = agg + (size_t)nodeG * 64;
    bf16x8 aa0 = *(const bf16x8*)(arow + 8 * q);
    bf16x8 aa1 = *(const bf16x8*)(arow + 32 + 8 * q);

    f32x4 acc[4];
#pragma unroll
    for (int ct = 0; ct < 4; ++ct) acc[ct] = (f32x4){bv[ct], bv[ct], bv[ct], bv[ct]};
#pragma unroll
    for (int ct = 0; ct < 4; ++ct) {
      acc[ct] = __builtin_amdgcn_mfma_f32_16x16x32_bf16(ax0, br[0][ct], acc[ct], 0, 0, 0);
      acc[ct] = __builtin_amdgcn_mfma_f32_16x16x32_bf16(ax1, br[1][ct], acc[ct], 0, 0, 0);
      acc[ct] = __builtin_amdgcn_mfma_f32_16x16x32_bf16(aa0, bl[0][ct], acc[ct], 0, 0, 0);
      acc[ct] = __builtin_amdgcn_mfma_f32_16x16x32_bf16(aa1, bl[1][ct], acc[ct], 0, 0, 0);
    }
    // D: row = 4*q + r, col = 16*ct + m
    int nodeRow0 = nodeBase + t * 16;
#pragma unroll
    for (int ct = 0; ct < 4; ++ct)
#pragma unroll
      for (int r = 0; r < 4; ++r) {
        float v = acc[ct][r];
        v = v > 0.0f ? v : 0.0f;
        xout[(size_t)(nodeRow0 + 4 * q + r) * 64 + 16 * ct + m] = f2b(v);
      }
  }
}

// ---------------- link scores: (1/9) * dot(sum_p, sum_t) --------------------
__global__ void score_kernel(const int* __restrict__ ell_pl,
                             const int* __restrict__ ell_tr,
                             const float* __restrict__ emb_pl,
                             const float* __restrict__ emb_tr,
                             const uint16_t* __restrict__ x1,
                             const uint16_t* __restrict__ x2,
                             float* __restrict__ out, int EP, int NP) {
  long g = (long)blockIdx.x * blockDim.x + threadIdx.x;
  long pair = g >> 4;
  int c = (int)(g & 15);
  if (pair >= EP) return;
  int p = ell_pl[pair];
  int t = ell_tr[pair];
  int d0 = c * 4;

  size_t pg = (size_t)p * 64 + d0;
  f32x4 sp = load4f(emb_pl + pg);
  f32x4 a = load4f(x1 + pg);
  f32x4 b = load4f(x2 + pg);
  sp.x += a.x + b.x; sp.y += a.y + b.y; sp.z += a.z + b.z; sp.w += a.w + b.w;

  size_t tl = (size_t)t * 64 + d0;
  size_t tg = (size_t)(NP + t) * 64 + d0;
  f32x4 st = load4f(emb_tr + tl);
  a = load4f(x1 + tg);
  b = load4f(x2 + tg);
  st.x += a.x + b.x; st.y += a.y + b.y; st.z += a.z + b.z; st.w += a.w + b.w;

  float partial = sp.x * st.x + sp.y * st.y + sp.z * st.z + sp.w * st.w;
  partial += __shfl_xor(partial, 1);
  partial += __shfl_xor(partial, 2);
  partial += __shfl_xor(partial, 4);
  partial += __shfl_xor(partial, 8);
  if (c == 0) out[pair] = partial * (1.0f / 9.0f);
}

extern "C" void kernel_launch(void* const* d_in, const int* in_sizes, int n_in,
                              void* d_out, int out_size, void* d_ws, size_t ws_size,
                              hipStream_t stream) {
  const float* emb_pl = (const float*)d_in[0];
  const float* emb_tr = (const float*)d_in[1];
  const float* W_rel = (const float*)d_in[2];   // [L,2,64,64] f32
  const float* W_root = (const float*)d_in[3];  // [L,64,64] f32
  const float* bias = (const float*)d_in[4];    // [L,64] f32
  const int* pt_src = (const int*)d_in[7];
  const int* pt_dst = (const int*)d_in[8];
  const int* tp_src = (const int*)d_in[9];
  const int* tp_dst = (const int*)d_in[10];
  const int* ell_pl = (const int*)d_in[11];
  const int* ell_tr = (const int*)d_in[12];
  float* out = (float*)d_out;

  const int NP = in_sizes[5];
  const int NT = in_sizes[6];
  const int E = in_sizes[7];
  const int EP = in_sizes[11];
  const int N = NP + NT;
  const int TE = 2 * E;

  char* ws = (char*)d_ws;
  size_t off = 0;
  uint16_t* agg = (uint16_t*)(ws + off); off += (size_t)N * 64 * 2;   // bf16
  uint16_t* x1  = (uint16_t*)(ws + off); off += (size_t)N * 64 * 2;   // bf16
  uint16_t* x2  = (uint16_t*)(ws + off); off += (size_t)N * 64 * 2;   // bf16
  int* cnt      = (int*)(ws + off);      off += (size_t)N * 4;
  int* rowptr   = (int*)(ws + off);      off += (size_t)(N + 1) * 4;
  int* wo       = (int*)(ws + off);      off += (size_t)N * 4;
  int* blockSums= (int*)(ws + off);      off += 1024 * 4;
  int* col      = (int*)(ws + off);      off += (size_t)TE * 4;

  const int TB = 256;
  int edgeBlocks = (TE + TB - 1) / TB;
  int nb = (N + 1023) / 1024;                 // 391 <= 1024
  int pullBlocks = (N + 3) / 4;
  int scoreBlocks = (int)(((long)EP * 16 + TB - 1) / TB);
  const int BP = 256, GT = 1024;              // transform grid split

  // ---- CSR build ----
  hipMemsetAsync(cnt, 0, (size_t)N * 4, stream);
  count_kernel<<<edgeBlocks, TB, 0, stream>>>(pt_dst, tp_dst, cnt, E, NP);
  partial_sum_kernel<<<nb, TB, 0, stream>>>(cnt, blockSums, N);
  scan_sums_kernel<<<1, 1024, 0, stream>>>(blockSums, nb);
  scan_chunk_kernel<<<nb, TB, 0, stream>>>(cnt, blockSums, rowptr, wo, N, TE);
  fill_kernel<<<edgeBlocks, TB, 0, stream>>>(pt_src, pt_dst, tp_src, tp_dst,
                                             wo, col, E, NP);

  // ---- layer 0 (x = fp32 embeddings) ----
  // node<NP pulls track rows (col>=NP): base = emb_tr - NP*64
  const float* basePl0 = (const float*)((const char*)emb_tr -
                                        (size_t)NP * 64 * sizeof(float));
  pull_kernel<float><<<pullBlocks, TB, 0, stream>>>(rowptr, col, basePl0,
                                                    emb_pl, agg, N, NP);
  transform_kernel<float><<<GT, TB, 0, stream>>>(
      emb_pl, emb_tr, agg, W_root + 0 * 4096, W_rel + 1 * 4096,
      W_rel + 0 * 4096, bias + 0, x1, NP, NT, BP);

  // ---- layer 1 (x = x1, bf16, global col indexing) ----
  pull_kernel<uint16_t><<<pullBlocks, TB, 0, stream>>>(rowptr, col, x1, x1,
                                                       agg, N, NP);
  transform_kernel<uint16_t><<<GT, TB, 0, stream>>>(
      x1, x1 + (size_t)NP * 64, agg, W_root + 1 * 4096, W_rel + 3 * 4096,
      W_rel + 2 * 4096, bias + 64, x2, NP, NT, BP);

  // ---- link scores ----
  score_kernel<<<scoreBlocks, TB, 0, stream>>>(ell_pl, ell_tr, emb_pl, emb_tr,
                                               x1, x2, out, EP, NP);
}